// Round 11
// baseline (268.326 us; speedup 1.0000x reference)
//
#include <hip/hip_runtime.h>

#define FDIM 128

typedef __attribute__((ext_vector_type(8))) short bf16x8;
typedef __attribute__((ext_vector_type(4))) float f32x4;
typedef __attribute__((ext_vector_type(2))) float f32x2;
typedef __attribute__((ext_vector_type(4))) unsigned int u32x4;
typedef __attribute__((ext_vector_type(2))) unsigned int u32x2;

// Column permutation for internal Z/S storage (within a 128-col half):
//   orig c: ct=c>>4, n=c&15  ->  stored s = 64*(ct>=4) + n*4 + (ct&3)
//   inv:    hi=s>>6, s6=s&63, n=s6>>2, ctl=s6&3 -> c = (ctl+4*hi)*16 + n

__device__ __forceinline__ unsigned short f2bf(float f){
  unsigned int u = __float_as_uint(f);
  unsigned int r = u + 0x7FFFu + ((u >> 16) & 1u);
  return (unsigned short)(r >> 16);
}

// ---------------- init: zero cnt, zero dummy Z/Z2 rows, build Wcat ----------------
__global__ void k_init(const float* __restrict__ Wl0, const float* __restrict__ Wr0,
                       const float* __restrict__ Wl1, const float* __restrict__ Wr1,
                       unsigned short* __restrict__ Wcat, int* __restrict__ cnt,
                       unsigned short* __restrict__ Zdummy, unsigned short* __restrict__ Z2dummy,
                       int N, int nb){
  int b = blockIdx.x;
  if (b < nb){
    int i = b*256 + threadIdx.x;
    if (i < N) cnt[i] = 0;
    if (b == 0 && threadIdx.x < FDIM){
      Zdummy[threadIdx.x]  = 0;
      Z2dummy[threadIdx.x] = 0;
    }
  } else {
    int i = (b - nb)*256 + threadIdx.x;     // 0 .. 65535
    int l   = i >> 15;
    int rem = i & 32767;
    int row = rem >> 7, k = rem & 127;
    int ksrc = k;
    if (l == 1){
      int hi = k >> 6, s6 = k & 63;
      ksrc = ((s6 & 3) + 4*hi)*16 + (s6 >> 2);   // invPerm(k)
    }
    const float* W = (l == 0) ? ((row < 128) ? Wl0 : Wr0)
                              : ((row < 128) ? Wl1 : Wr1);
    Wcat[i] = f2bf(W[(row & 127)*128 + ksrc]);
  }
}

// ---------------- hierarchical scan over PADDED degrees ----------------
// writes per-node exclusive-in-tile to row_off, raw tile total to partials[b]
__global__ void k_scan_blocks(const int* __restrict__ cnt, int* __restrict__ excl,
                              int* __restrict__ partials, int N){
  __shared__ int s[256];
  int tid = threadIdx.x;
  int i = blockIdx.x*256 + tid;
  int v = (i < N) ? ((cnt[i] + 7) & ~7) : 0;
  s[tid] = v; __syncthreads();
  for (int off = 1; off < 256; off <<= 1){
    int t = (tid >= off) ? s[tid - off] : 0;
    __syncthreads();
    s[tid] += t;
    __syncthreads();
  }
  if (i < N) excl[i] = s[tid] - v;
  if (tid == 255) partials[blockIdx.x] = s[255];
}

// finalize + pad, with SELF-COMPUTED tile prefix (R16: folds k_scan_partials
// into this kernel — each block sums partials[0..b-1], <=391 reads, then
// block-reduces; eliminates a launch+drain).
__global__ void k_finalize_pad(int* __restrict__ row_off, const int* __restrict__ partials,
                               int* __restrict__ cursor, const int* __restrict__ cnt,
                               int* __restrict__ csr_src, int N){
  __shared__ int red[256];
  int tid = threadIdx.x;
  int acc = 0;
  for (int i = tid; i < blockIdx.x; i += 256) acc += partials[i];
  red[tid] = acc; __syncthreads();
  for (int off = 128; off > 0; off >>= 1){
    if (tid < off) red[tid] += red[tid + off];
    __syncthreads();
  }
  int prefix = red[0];

  int i = blockIdx.x*256 + tid;
  if (i >= N) return;
  int ro = row_off[i] + prefix;
  row_off[i] = ro;
  cursor[i]  = ro;
  int d  = cnt[i];
  int pd = (d + 7) & ~7;
  for (int p = d; p < pd; p++) csr_src[ro + p] = N;
}

// ---------------- fill ----------------
__global__ void k_fill(const int* __restrict__ src, const int* __restrict__ dst,
                       int* __restrict__ cursor, int* __restrict__ csr_src, int E){
  int e = blockIdx.x*256 + threadIdx.x;
  if (e >= E) return;
  int d = dst[e];
  int pos = atomicAdd(&cursor[d], 1);
  csr_src[pos] = src[e];
}

// ---------------- layer-1 dual GEMM + fused degree count ----------------
// R16: phase-0 grid-stride degree slice over E fused in (atomics are
// fire-and-forget -> overlap the GEMM's loads instead of a serial launch).
// R13 config kept: grid 512, (256,2); X cached, S stores NT, Z stores cached.
__global__ __launch_bounds__(256, 2)
void k_dualgemm1(const float* __restrict__ X, const unsigned short* __restrict__ Wcat,
                 const float* __restrict__ bl, const float* __restrict__ br,
                 unsigned short* __restrict__ Z, unsigned short* __restrict__ S,
                 const int* __restrict__ dst, int* __restrict__ cnt, int E,
                 int N, int nrb){
  __shared__ unsigned short lds[64*FDIM];
  const int tid  = threadIdx.x;
  const int wave = tid >> 6;
  const int lane = tid & 63;
  const int n = lane & 15, q = lane >> 4;

  // phase 0: degree slice (independent of GEMM; atomics overlap loads below)
  for (int e = blockIdx.x*256 + tid; e < E; e += gridDim.x*256)
    atomicAdd(&cnt[dst[e]], 1);

  float bias[4];
#pragma unroll
  for (int ctl = 0; ctl < 4; ctl++){
    int ct = wave*4 + ctl;
    if (ct >= 8){ int col = (ct - 8)*16 + n; bias[ctl] = bl[col] + br[col]; }
    else bias[ctl] = 0.0f;
  }

  f32x4 pf[8];
  const int r_   = tid >> 4;
  const int c16_ = tid & 15;

  auto issue_load = [&](int rb){
    int row0 = rb*64;
#pragma unroll
    for (int it = 0; it < 4; it++){
      int r  = r_ + it*16;
      int gr = row0 + r;
      if (gr < N){
        const f32x4* sp = (const f32x4*)(X + (size_t)gr*FDIM + c16_*8);
        pf[2*it]   = sp[0];
        pf[2*it+1] = sp[1];
      } else {
        pf[2*it]   = (f32x4){0.f,0.f,0.f,0.f};
        pf[2*it+1] = (f32x4){0.f,0.f,0.f,0.f};
      }
    }
  };

  int rb = blockIdx.x;
  if (rb < nrb) issue_load(rb);

  for (; rb < nrb; rb += gridDim.x){
    int row0 = rb*64;
    __syncthreads();
#pragma unroll
    for (int it = 0; it < 4; it++){
      int r = r_ + it*16;
      f32x4 v0 = pf[2*it], v1 = pf[2*it+1];
      bf16x8 p;
      p[0] = (short)f2bf(v0[0]); p[1] = (short)f2bf(v0[1]);
      p[2] = (short)f2bf(v0[2]); p[3] = (short)f2bf(v0[3]);
      p[4] = (short)f2bf(v1[0]); p[5] = (short)f2bf(v1[1]);
      p[6] = (short)f2bf(v1[2]); p[7] = (short)f2bf(v1[3]);
      *(bf16x8*)(lds + r*FDIM + ((c16_ ^ (r & 15)) * 8)) = p;
    }
    __syncthreads();

    int rbn = rb + gridDim.x;
    if (rbn < nrb) issue_load(rbn);

    f32x4 acc[4][4];
#pragma unroll
    for (int rt = 0; rt < 4; rt++)
#pragma unroll
      for (int ctl = 0; ctl < 4; ctl++)
        acc[rt][ctl] = (f32x4){0.f, 0.f, 0.f, 0.f};

#pragma unroll
    for (int kk = 0; kk < 4; kk++){
      bf16x8 bfr[4];
#pragma unroll
      for (int ctl = 0; ctl < 4; ctl++){
        int row = (wave*4 + ctl)*16 + n;
        bfr[ctl] = *(const bf16x8*)(Wcat + row*FDIM + kk*32 + q*8);
      }
      bf16x8 afr[4];
#pragma unroll
      for (int rt = 0; rt < 4; rt++){
        int r = rt*16 + n;
        int c16 = (kk*4 + q) ^ n;
        afr[rt] = *(const bf16x8*)(lds + r*FDIM + c16*8);
      }
#pragma unroll
      for (int rt = 0; rt < 4; rt++)
#pragma unroll
        for (int ctl = 0; ctl < 4; ctl++)
          acc[rt][ctl] = __builtin_amdgcn_mfma_f32_16x16x32_bf16(
              afr[rt], bfr[ctl], acc[rt][ctl], 0, 0, 0);
    }

    unsigned short* dstb = (wave < 2) ? Z : S;
    int s0 = 64*(wave & 1) + n*4;
#pragma unroll
    for (int rt = 0; rt < 4; rt++){
#pragma unroll
      for (int r = 0; r < 4; r++){
        int grow = row0 + rt*16 + q*4 + r;
        if (grow < N){
          float v0 = acc[rt][0][r] + bias[0];
          float v1 = acc[rt][1][r] + bias[1];
          float v2 = acc[rt][2][r] + bias[2];
          float v3 = acc[rt][3][r] + bias[3];
          u32x2 u;
          u[0] = ((unsigned)f2bf(v1) << 16) | (unsigned)f2bf(v0);
          u[1] = ((unsigned)f2bf(v3) << 16) | (unsigned)f2bf(v2);
          u32x2* dp = (u32x2*)(dstb + (size_t)grow*FDIM + s0);
          if (wave < 2) *dp = u;                         // Z: cached (gathered next)
          else __builtin_nontemporal_store(u, dp);       // S: stream
        }
      }
    }
  }
}

// ---------------- layer-1 aggregate only (un-fused, zero-LDS; R14 win) ----------------
// h = relu(mean(Z[src]) + S) written IN PLACE over S (own row only).
__global__ __launch_bounds__(256)
void k_agg1(const unsigned short* __restrict__ Z, unsigned short* __restrict__ S,
            const int* __restrict__ row_off, const int* __restrict__ cnt,
            const int* __restrict__ csr_src, int N){
  const int tid   = threadIdx.x;
  const int node  = blockIdx.x*16 + (tid >> 4);
  const int g16   = tid & 15;
  const int gbase = (tid & 63) & 48;
  if (node >= N) return;
  int ro   = row_off[node];
  int deg  = cnt[node];
  int pdeg = (deg + 7) & ~7;
  float inv = 1.0f / (float)(deg > 1 ? deg : 1);
  float hacc[8];
#pragma unroll
  for (int z = 0; z < 8; z++) hacc[z] = 0.f;

  for (int base = 0; base < pdeg; base += 16){
    int rem = pdeg - base;
    int sidx = (g16 < rem) ? csr_src[ro + base + g16] : N;   // pad/dummy -> zero row
    {
      uint4 v[8];
#pragma unroll
      for (int t = 0; t < 8; t++){
        int id = __shfl(sidx, gbase + t);
        v[t] = *(const uint4*)(Z + (size_t)(unsigned)id*FDIM + g16*8);
      }
#pragma unroll
      for (int t = 0; t < 8; t++){
        hacc[0] += __uint_as_float(v[t].x << 16);
        hacc[1] += __uint_as_float(v[t].x & 0xFFFF0000u);
        hacc[2] += __uint_as_float(v[t].y << 16);
        hacc[3] += __uint_as_float(v[t].y & 0xFFFF0000u);
        hacc[4] += __uint_as_float(v[t].z << 16);
        hacc[5] += __uint_as_float(v[t].z & 0xFFFF0000u);
        hacc[6] += __uint_as_float(v[t].w << 16);
        hacc[7] += __uint_as_float(v[t].w & 0xFFFF0000u);
      }
    }
    if (rem > 8){
      uint4 v[8];
#pragma unroll
      for (int t = 0; t < 8; t++){
        int id = __shfl(sidx, gbase + 8 + t);
        v[t] = *(const uint4*)(Z + (size_t)(unsigned)id*FDIM + g16*8);
      }
#pragma unroll
      for (int t = 0; t < 8; t++){
        hacc[0] += __uint_as_float(v[t].x << 16);
        hacc[1] += __uint_as_float(v[t].x & 0xFFFF0000u);
        hacc[2] += __uint_as_float(v[t].y << 16);
        hacc[3] += __uint_as_float(v[t].y & 0xFFFF0000u);
        hacc[4] += __uint_as_float(v[t].z << 16);
        hacc[5] += __uint_as_float(v[t].z & 0xFFFF0000u);
        hacc[6] += __uint_as_float(v[t].w << 16);
        hacc[7] += __uint_as_float(v[t].w & 0xFFFF0000u);
      }
    }
  }

  u32x4 sv = __builtin_nontemporal_load((const u32x4*)(S + (size_t)node*FDIM + g16*8));
  bf16x8 p;
  p[0] = (short)f2bf(fmaxf(hacc[0]*inv + __uint_as_float(sv[0] << 16),          0.f));
  p[1] = (short)f2bf(fmaxf(hacc[1]*inv + __uint_as_float(sv[0] & 0xFFFF0000u),  0.f));
  p[2] = (short)f2bf(fmaxf(hacc[2]*inv + __uint_as_float(sv[1] << 16),          0.f));
  p[3] = (short)f2bf(fmaxf(hacc[3]*inv + __uint_as_float(sv[1] & 0xFFFF0000u),  0.f));
  p[4] = (short)f2bf(fmaxf(hacc[4]*inv + __uint_as_float(sv[2] << 16),          0.f));
  p[5] = (short)f2bf(fmaxf(hacc[5]*inv + __uint_as_float(sv[2] & 0xFFFF0000u),  0.f));
  p[6] = (short)f2bf(fmaxf(hacc[6]*inv + __uint_as_float(sv[3] << 16),          0.f));
  p[7] = (short)f2bf(fmaxf(hacc[7]*inv + __uint_as_float(sv[3] & 0xFFFF0000u),  0.f));
  *(bf16x8*)(S + (size_t)node*FDIM + g16*8) = p;   // h (cached: read by k_gemm2)
}

// ---------------- layer-2 dual GEMM on bf16 h (streaming) ----------------
// R15: H loads cached (L2-hot from k_agg1). Z2 stores cached; S2 stores NT.
__global__ __launch_bounds__(256, 2)
void k_gemm2(const unsigned short* __restrict__ H, const unsigned short* __restrict__ Wcat,
             const float* __restrict__ bl, const float* __restrict__ br,
             unsigned short* __restrict__ Z2, unsigned short* __restrict__ S,
             int N, int nrb){
  __shared__ unsigned short lds[64*FDIM];
  const int tid  = threadIdx.x;
  const int wave = tid >> 6;
  const int lane = tid & 63;
  const int n = lane & 15, q = lane >> 4;

  float bias[4];
#pragma unroll
  for (int ctl = 0; ctl < 4; ctl++){
    int ct = wave*4 + ctl;
    if (ct >= 8){ int col = (ct - 8)*16 + n; bias[ctl] = bl[col] + br[col]; }
    else bias[ctl] = 0.0f;
  }

  u32x4 pf[4];
  const int r_   = tid >> 4;
  const int c16_ = tid & 15;

  auto issue_load = [&](int rb){
    int row0 = rb*64;
#pragma unroll
    for (int it = 0; it < 4; it++){
      int gr = row0 + r_ + it*16;
      if (gr < N)
        pf[it] = *(const u32x4*)(H + (size_t)gr*FDIM + c16_*8);
      else
        pf[it] = (u32x4){0u,0u,0u,0u};
    }
  };

  int rb = blockIdx.x;
  if (rb < nrb) issue_load(rb);

  for (; rb < nrb; rb += gridDim.x){
    int row0 = rb*64;
    __syncthreads();
#pragma unroll
    for (int it = 0; it < 4; it++){
      int r = r_ + it*16;
      *(u32x4*)(lds + r*FDIM + ((c16_ ^ (r & 15)) * 8)) = pf[it];
    }
    __syncthreads();

    int rbn = rb + gridDim.x;
    if (rbn < nrb) issue_load(rbn);

    f32x4 acc[4][4];
#pragma unroll
    for (int rt = 0; rt < 4; rt++)
#pragma unroll
      for (int ctl = 0; ctl < 4; ctl++)
        acc[rt][ctl] = (f32x4){0.f, 0.f, 0.f, 0.f};

#pragma unroll
    for (int kk = 0; kk < 4; kk++){
      bf16x8 bfr[4];
#pragma unroll
      for (int ctl = 0; ctl < 4; ctl++){
        int row = (wave*4 + ctl)*16 + n;
        bfr[ctl] = *(const bf16x8*)(Wcat + row*FDIM + kk*32 + q*8);
      }
      bf16x8 afr[4];
#pragma unroll
      for (int rt = 0; rt < 4; rt++){
        int r = rt*16 + n;
        int c16 = (kk*4 + q) ^ n;
        afr[rt] = *(const bf16x8*)(lds + r*FDIM + c16*8);
      }
#pragma unroll
      for (int rt = 0; rt < 4; rt++)
#pragma unroll
        for (int ctl = 0; ctl < 4; ctl++)
          acc[rt][ctl] = __builtin_amdgcn_mfma_f32_16x16x32_bf16(
              afr[rt], bfr[ctl], acc[rt][ctl], 0, 0, 0);
    }

    unsigned short* dstb = (wave < 2) ? Z2 : S;
    int s0c = 64*(wave & 1) + n*4;
#pragma unroll
    for (int rt = 0; rt < 4; rt++){
#pragma unroll
      for (int r = 0; r < 4; r++){
        int grow = row0 + rt*16 + q*4 + r;
        if (grow < N){
          float v0 = acc[rt][0][r] + bias[0];
          float v1 = acc[rt][1][r] + bias[1];
          float v2 = acc[rt][2][r] + bias[2];
          float v3 = acc[rt][3][r] + bias[3];
          u32x2 u;
          u[0] = ((unsigned)f2bf(v1) << 16) | (unsigned)f2bf(v0);
          u[1] = ((unsigned)f2bf(v3) << 16) | (unsigned)f2bf(v2);
          u32x2* dp = (u32x2*)(dstb + (size_t)grow*FDIM + s0c);
          if (wave < 2) *dp = u;                         // Z2: cached
          else __builtin_nontemporal_store(u, dp);       // S2: stream
        }
      }
    }
  }
}

// ---------------- final aggregate: out = relu(sum(Z2[src])/deg + S2) ----------------
// Zero-LDS group-per-node shape; paired float2 un-permute stores (R15 win).
__global__ __launch_bounds__(256)
void k_aggregate(const unsigned short* __restrict__ Z2, const unsigned short* __restrict__ S,
                 const int* __restrict__ row_off, const int* __restrict__ cnt,
                 const int* __restrict__ csr_src, float* __restrict__ Out, int N){
  const int tid   = threadIdx.x;
  const int node  = blockIdx.x*16 + (tid >> 4);
  const int g16   = tid & 15;
  const int gbase = (tid & 63) & 48;
  if (node >= N) return;
  int ro   = row_off[node];
  int deg  = cnt[node];
  int pdeg = (deg + 7) & ~7;
  float inv = 1.0f / (float)(deg > 1 ? deg : 1);
  float hacc[8];
#pragma unroll
  for (int z = 0; z < 8; z++) hacc[z] = 0.f;

  for (int base = 0; base < pdeg; base += 16){
    int rem = pdeg - base;
    int sidx = (g16 < rem) ? csr_src[ro + base + g16] : N;
    {
      uint4 v[8];
#pragma unroll
      for (int t = 0; t < 8; t++){
        int id = __shfl(sidx, gbase + t);
        v[t] = *(const uint4*)(Z2 + (size_t)(unsigned)id*FDIM + g16*8);
      }
#pragma unroll
      for (int t = 0; t < 8; t++){
        hacc[0] += __uint_as_float(v[t].x << 16);
        hacc[1] += __uint_as_float(v[t].x & 0xFFFF0000u);
        hacc[2] += __uint_as_float(v[t].y << 16);
        hacc[3] += __uint_as_float(v[t].y & 0xFFFF0000u);
        hacc[4] += __uint_as_float(v[t].z << 16);
        hacc[5] += __uint_as_float(v[t].z & 0xFFFF0000u);
        hacc[6] += __uint_as_float(v[t].w << 16);
        hacc[7] += __uint_as_float(v[t].w & 0xFFFF0000u);
      }
    }
    if (rem > 8){
      uint4 v[8];
#pragma unroll
      for (int t = 0; t < 8; t++){
        int id = __shfl(sidx, gbase + 8 + t);
        v[t] = *(const uint4*)(Z2 + (size_t)(unsigned)id*FDIM + g16*8);
      }
#pragma unroll
      for (int t = 0; t < 8; t++){
        hacc[0] += __uint_as_float(v[t].x << 16);
        hacc[1] += __uint_as_float(v[t].x & 0xFFFF0000u);
        hacc[2] += __uint_as_float(v[t].y << 16);
        hacc[3] += __uint_as_float(v[t].y & 0xFFFF0000u);
        hacc[4] += __uint_as_float(v[t].z << 16);
        hacc[5] += __uint_as_float(v[t].z & 0xFFFF0000u);
        hacc[6] += __uint_as_float(v[t].w << 16);
        hacc[7] += __uint_as_float(v[t].w & 0xFFFF0000u);
      }
    }
  }

  u32x4 sv = __builtin_nontemporal_load((const u32x4*)(S + (size_t)node*FDIM + g16*8));
  float o[8];
  o[0] = fmaxf(hacc[0]*inv + __uint_as_float(sv[0] << 16),          0.f);
  o[1] = fmaxf(hacc[1]*inv + __uint_as_float(sv[0] & 0xFFFF0000u),  0.f);
  o[2] = fmaxf(hacc[2]*inv + __uint_as_float(sv[1] << 16),          0.f);
  o[3] = fmaxf(hacc[3]*inv + __uint_as_float(sv[1] & 0xFFFF0000u),  0.f);
  o[4] = fmaxf(hacc[4]*inv + __uint_as_float(sv[2] << 16),          0.f);
  o[5] = fmaxf(hacc[5]*inv + __uint_as_float(sv[2] & 0xFFFF0000u),  0.f);
  o[6] = fmaxf(hacc[6]*inv + __uint_as_float(sv[3] << 16),          0.f);
  o[7] = fmaxf(hacc[7]*inv + __uint_as_float(sv[3] & 0xFFFF0000u),  0.f);
  // un-permute via paired float2 stores: pair k = (o[k], o[k+4]) at base + k*16
  int obase = 64*(g16 >> 3) + (g16 & 7)*2;
#pragma unroll
  for (int k = 0; k < 4; k++){
    f32x2 w; w[0] = o[k]; w[1] = o[k+4];
    __builtin_nontemporal_store(w, (f32x2*)(Out + (size_t)node*FDIM + obase + k*16));
  }
}

extern "C" void kernel_launch(void* const* d_in, const int* in_sizes, int n_in,
                              void* d_out, int out_size, void* d_ws, size_t ws_size,
                              hipStream_t stream){
  const float* x   = (const float*)d_in[0];
  const int*   eix = (const int*)d_in[1];
  const float* Wl0 = (const float*)d_in[2];
  const float* bl0 = (const float*)d_in[3];
  const float* Wr0 = (const float*)d_in[4];
  const float* br0 = (const float*)d_in[5];
  const float* Wl1 = (const float*)d_in[6];
  const float* bl1 = (const float*)d_in[7];
  const float* Wr1 = (const float*)d_in[8];
  const float* br1 = (const float*)d_in[9];
  float* out = (float*)d_out;

  int N = in_sizes[0] / FDIM;
  int E = in_sizes[1] / 2;
  const int* src = eix;
  const int* dst = eix + E;

  // workspace (Z and Z2 have N+1 rows: row N is the zero dummy row)
  unsigned short* Z    = (unsigned short*)d_ws;
  unsigned short* Z2   = Z  + (size_t)(N + 1)*FDIM;
  unsigned short* S    = Z2 + (size_t)(N + 1)*FDIM;
  unsigned short* Wcat = S  + (size_t)N*FDIM;
  int* cnt     = (int*)(Wcat + 2*256*128);
  int* row_off = cnt + N;
  int* cursor  = row_off + N;
  int* csr_src = cursor + N;                 // capacity: E + 7N (padding bound)
  int* partials= csr_src + (E + 7*N);

  int nb = (N + 255)/256;

  k_init         <<<nb + 256, 256, 0, stream>>>(Wl0, Wr0, Wl1, Wr1, Wcat, cnt,
                                                Z + (size_t)N*FDIM, Z2 + (size_t)N*FDIM, N, nb);

  int nrb  = (N + 63)/64;
  int ngrp = (N + 15)/16;
  // degree counting fused into dualgemm1 (phase 0); scan chain follows it
  k_dualgemm1    <<<512, 256, 0, stream>>>(x, Wcat, bl0, br0, Z, S, dst, cnt, E, N, nrb);
  k_scan_blocks  <<<nb, 256, 0, stream>>>(cnt, row_off, partials, N);
  k_finalize_pad <<<nb, 256, 0, stream>>>(row_off, partials, cursor, cnt, csr_src, N);
  k_fill         <<<(E + 255)/256, 256, 0, stream>>>(src, dst, cursor, csr_src, E);

  k_agg1     <<<ngrp, 256, 0, stream>>>(Z, S, row_off, cnt, csr_src, N);
  k_gemm2    <<<512, 256, 0, stream>>>(S, Wcat + 256*128, bl1, br1, Z2, S, N, nrb);
  k_aggregate<<<ngrp, 256, 0, stream>>>(Z2, S, row_off, cnt, csr_src, out, N);
}

// Round 13
// 267.352 us; speedup vs baseline: 1.0036x; 1.0036x over previous
//
#include <hip/hip_runtime.h>

#define FDIM 128

typedef __attribute__((ext_vector_type(8))) short bf16x8;
typedef __attribute__((ext_vector_type(4))) float f32x4;
typedef __attribute__((ext_vector_type(2))) float f32x2;
typedef __attribute__((ext_vector_type(4))) unsigned int u32x4;
typedef __attribute__((ext_vector_type(2))) unsigned int u32x2;

// Column permutation for internal Z/S storage (within a 128-col half):
//   orig c: ct=c>>4, n=c&15  ->  stored s = 64*(ct>=4) + n*4 + (ct&3)
//   inv:    hi=s>>6, s6=s&63, n=s6>>2, ctl=s6&3 -> c = (ctl+4*hi)*16 + n

__device__ __forceinline__ unsigned short f2bf(float f){
  unsigned int u = __float_as_uint(f);
  unsigned int r = u + 0x7FFFu + ((u >> 16) & 1u);
  return (unsigned short)(r >> 16);
}

// ---------------- init: zero cnt, zero dummy Z/Z2 rows, build Wcat ----------------
__global__ void k_init(const float* __restrict__ Wl0, const float* __restrict__ Wr0,
                       const float* __restrict__ Wl1, const float* __restrict__ Wr1,
                       unsigned short* __restrict__ Wcat, int* __restrict__ cnt,
                       unsigned short* __restrict__ Zdummy, unsigned short* __restrict__ Z2dummy,
                       int N, int nb){
  int b = blockIdx.x;
  if (b < nb){
    int i = b*256 + threadIdx.x;
    if (i < N) cnt[i] = 0;
    if (b == 0 && threadIdx.x < FDIM){
      Zdummy[threadIdx.x]  = 0;
      Z2dummy[threadIdx.x] = 0;
    }
  } else {
    int i = (b - nb)*256 + threadIdx.x;     // 0 .. 65535
    int l   = i >> 15;
    int rem = i & 32767;
    int row = rem >> 7, k = rem & 127;
    int ksrc = k;
    if (l == 1){
      int hi = k >> 6, s6 = k & 63;
      ksrc = ((s6 & 3) + 4*hi)*16 + (s6 >> 2);   // invPerm(k)
    }
    const float* W = (l == 0) ? ((row < 128) ? Wl0 : Wr0)
                              : ((row < 128) ? Wl1 : Wr1);
    Wcat[i] = f2bf(W[(row & 127)*128 + ksrc]);
  }
}

// ---------------- degree (standalone again — R17: the R16 fusion serialized
// the atomic scatter at 2-blocks/CU inside dualgemm1 and cost ~10us; at 2344
// blocks the atomics get full-device TLP) ----------------
__global__ void k_degree(const int* __restrict__ dst, int* __restrict__ cnt, int E){
  int e = blockIdx.x*256 + threadIdx.x;
  if (e < E) atomicAdd(&cnt[dst[e]], 1);
}

// ---------------- hierarchical scan over PADDED degrees ----------------
__global__ void k_scan_blocks(const int* __restrict__ cnt, int* __restrict__ excl,
                              int* __restrict__ partials, int N){
  __shared__ int s[256];
  int tid = threadIdx.x;
  int i = blockIdx.x*256 + tid;
  int v = (i < N) ? ((cnt[i] + 7) & ~7) : 0;
  s[tid] = v; __syncthreads();
  for (int off = 1; off < 256; off <<= 1){
    int t = (tid >= off) ? s[tid - off] : 0;
    __syncthreads();
    s[tid] += t;
    __syncthreads();
  }
  if (i < N) excl[i] = s[tid] - v;
  if (tid == 255) partials[blockIdx.x] = s[255];
}

// finalize + pad, with SELF-COMPUTED tile prefix (R16 keep: folds
// k_scan_partials in — each block sums partials[0..b-1], then block-reduces;
// eliminates a launch+drain with no downside).
__global__ void k_finalize_pad(int* __restrict__ row_off, const int* __restrict__ partials,
                               int* __restrict__ cursor, const int* __restrict__ cnt,
                               int* __restrict__ csr_src, int N){
  __shared__ int red[256];
  int tid = threadIdx.x;
  int acc = 0;
  for (int i = tid; i < blockIdx.x; i += 256) acc += partials[i];
  red[tid] = acc; __syncthreads();
  for (int off = 128; off > 0; off >>= 1){
    if (tid < off) red[tid] += red[tid + off];
    __syncthreads();
  }
  int prefix = red[0];

  int i = blockIdx.x*256 + tid;
  if (i >= N) return;
  int ro = row_off[i] + prefix;
  row_off[i] = ro;
  cursor[i]  = ro;
  int d  = cnt[i];
  int pd = (d + 7) & ~7;
  for (int p = d; p < pd; p++) csr_src[ro + p] = N;
}

// ---------------- fill ----------------
__global__ void k_fill(const int* __restrict__ src, const int* __restrict__ dst,
                       int* __restrict__ cursor, int* __restrict__ csr_src, int E){
  int e = blockIdx.x*256 + threadIdx.x;
  if (e >= E) return;
  int d = dst[e];
  int pos = atomicAdd(&cursor[d], 1);
  csr_src[pos] = src[e];
}

// ---------------- layer-1 dual GEMM: Z = X@Wl^T, S = X@Wr^T + (bl+br) ----------------
// R13 config: grid 512, (256,2); X cached, S stores NT, Z stores cached.
__global__ __launch_bounds__(256, 2)
void k_dualgemm1(const float* __restrict__ X, const unsigned short* __restrict__ Wcat,
                 const float* __restrict__ bl, const float* __restrict__ br,
                 unsigned short* __restrict__ Z, unsigned short* __restrict__ S,
                 int N, int nrb){
  __shared__ unsigned short lds[64*FDIM];
  const int tid  = threadIdx.x;
  const int wave = tid >> 6;
  const int lane = tid & 63;
  const int n = lane & 15, q = lane >> 4;

  float bias[4];
#pragma unroll
  for (int ctl = 0; ctl < 4; ctl++){
    int ct = wave*4 + ctl;
    if (ct >= 8){ int col = (ct - 8)*16 + n; bias[ctl] = bl[col] + br[col]; }
    else bias[ctl] = 0.0f;
  }

  f32x4 pf[8];
  const int r_   = tid >> 4;
  const int c16_ = tid & 15;

  auto issue_load = [&](int rb){
    int row0 = rb*64;
#pragma unroll
    for (int it = 0; it < 4; it++){
      int r  = r_ + it*16;
      int gr = row0 + r;
      if (gr < N){
        const f32x4* sp = (const f32x4*)(X + (size_t)gr*FDIM + c16_*8);
        pf[2*it]   = sp[0];
        pf[2*it+1] = sp[1];
      } else {
        pf[2*it]   = (f32x4){0.f,0.f,0.f,0.f};
        pf[2*it+1] = (f32x4){0.f,0.f,0.f,0.f};
      }
    }
  };

  int rb = blockIdx.x;
  if (rb < nrb) issue_load(rb);

  for (; rb < nrb; rb += gridDim.x){
    int row0 = rb*64;
    __syncthreads();
#pragma unroll
    for (int it = 0; it < 4; it++){
      int r = r_ + it*16;
      f32x4 v0 = pf[2*it], v1 = pf[2*it+1];
      bf16x8 p;
      p[0] = (short)f2bf(v0[0]); p[1] = (short)f2bf(v0[1]);
      p[2] = (short)f2bf(v0[2]); p[3] = (short)f2bf(v0[3]);
      p[4] = (short)f2bf(v1[0]); p[5] = (short)f2bf(v1[1]);
      p[6] = (short)f2bf(v1[2]); p[7] = (short)f2bf(v1[3]);
      *(bf16x8*)(lds + r*FDIM + ((c16_ ^ (r & 15)) * 8)) = p;
    }
    __syncthreads();

    int rbn = rb + gridDim.x;
    if (rbn < nrb) issue_load(rbn);

    f32x4 acc[4][4];
#pragma unroll
    for (int rt = 0; rt < 4; rt++)
#pragma unroll
      for (int ctl = 0; ctl < 4; ctl++)
        acc[rt][ctl] = (f32x4){0.f, 0.f, 0.f, 0.f};

#pragma unroll
    for (int kk = 0; kk < 4; kk++){
      bf16x8 bfr[4];
#pragma unroll
      for (int ctl = 0; ctl < 4; ctl++){
        int row = (wave*4 + ctl)*16 + n;
        bfr[ctl] = *(const bf16x8*)(Wcat + row*FDIM + kk*32 + q*8);
      }
      bf16x8 afr[4];
#pragma unroll
      for (int rt = 0; rt < 4; rt++){
        int r = rt*16 + n;
        int c16 = (kk*4 + q) ^ n;
        afr[rt] = *(const bf16x8*)(lds + r*FDIM + c16*8);
      }
#pragma unroll
      for (int rt = 0; rt < 4; rt++)
#pragma unroll
        for (int ctl = 0; ctl < 4; ctl++)
          acc[rt][ctl] = __builtin_amdgcn_mfma_f32_16x16x32_bf16(
              afr[rt], bfr[ctl], acc[rt][ctl], 0, 0, 0);
    }

    unsigned short* dstb = (wave < 2) ? Z : S;
    int s0 = 64*(wave & 1) + n*4;
#pragma unroll
    for (int rt = 0; rt < 4; rt++){
#pragma unroll
      for (int r = 0; r < 4; r++){
        int grow = row0 + rt*16 + q*4 + r;
        if (grow < N){
          float v0 = acc[rt][0][r] + bias[0];
          float v1 = acc[rt][1][r] + bias[1];
          float v2 = acc[rt][2][r] + bias[2];
          float v3 = acc[rt][3][r] + bias[3];
          u32x2 u;
          u[0] = ((unsigned)f2bf(v1) << 16) | (unsigned)f2bf(v0);
          u[1] = ((unsigned)f2bf(v3) << 16) | (unsigned)f2bf(v2);
          u32x2* dp = (u32x2*)(dstb + (size_t)grow*FDIM + s0);
          if (wave < 2) *dp = u;                         // Z: cached (gathered next)
          else __builtin_nontemporal_store(u, dp);       // S: stream
        }
      }
    }
  }
}

// ---------------- layer-1 aggregate only (un-fused, zero-LDS; R14 win) ----------------
// h = relu(mean(Z[src]) + S) written IN PLACE over S (own row only).
__global__ __launch_bounds__(256)
void k_agg1(const unsigned short* __restrict__ Z, unsigned short* __restrict__ S,
            const int* __restrict__ row_off, const int* __restrict__ cnt,
            const int* __restrict__ csr_src, int N){
  const int tid   = threadIdx.x;
  const int node  = blockIdx.x*16 + (tid >> 4);
  const int g16   = tid & 15;
  const int gbase = (tid & 63) & 48;
  if (node >= N) return;
  int ro   = row_off[node];
  int deg  = cnt[node];
  int pdeg = (deg + 7) & ~7;
  float inv = 1.0f / (float)(deg > 1 ? deg : 1);
  float hacc[8];
#pragma unroll
  for (int z = 0; z < 8; z++) hacc[z] = 0.f;

  for (int base = 0; base < pdeg; base += 16){
    int rem = pdeg - base;
    int sidx = (g16 < rem) ? csr_src[ro + base + g16] : N;   // pad/dummy -> zero row
    {
      uint4 v[8];
#pragma unroll
      for (int t = 0; t < 8; t++){
        int id = __shfl(sidx, gbase + t);
        v[t] = *(const uint4*)(Z + (size_t)(unsigned)id*FDIM + g16*8);
      }
#pragma unroll
      for (int t = 0; t < 8; t++){
        hacc[0] += __uint_as_float(v[t].x << 16);
        hacc[1] += __uint_as_float(v[t].x & 0xFFFF0000u);
        hacc[2] += __uint_as_float(v[t].y << 16);
        hacc[3] += __uint_as_float(v[t].y & 0xFFFF0000u);
        hacc[4] += __uint_as_float(v[t].z << 16);
        hacc[5] += __uint_as_float(v[t].z & 0xFFFF0000u);
        hacc[6] += __uint_as_float(v[t].w << 16);
        hacc[7] += __uint_as_float(v[t].w & 0xFFFF0000u);
      }
    }
    if (rem > 8){
      uint4 v[8];
#pragma unroll
      for (int t = 0; t < 8; t++){
        int id = __shfl(sidx, gbase + 8 + t);
        v[t] = *(const uint4*)(Z + (size_t)(unsigned)id*FDIM + g16*8);
      }
#pragma unroll
      for (int t = 0; t < 8; t++){
        hacc[0] += __uint_as_float(v[t].x << 16);
        hacc[1] += __uint_as_float(v[t].x & 0xFFFF0000u);
        hacc[2] += __uint_as_float(v[t].y << 16);
        hacc[3] += __uint_as_float(v[t].y & 0xFFFF0000u);
        hacc[4] += __uint_as_float(v[t].z << 16);
        hacc[5] += __uint_as_float(v[t].z & 0xFFFF0000u);
        hacc[6] += __uint_as_float(v[t].w << 16);
        hacc[7] += __uint_as_float(v[t].w & 0xFFFF0000u);
      }
    }
  }

  u32x4 sv = __builtin_nontemporal_load((const u32x4*)(S + (size_t)node*FDIM + g16*8));
  bf16x8 p;
  p[0] = (short)f2bf(fmaxf(hacc[0]*inv + __uint_as_float(sv[0] << 16),          0.f));
  p[1] = (short)f2bf(fmaxf(hacc[1]*inv + __uint_as_float(sv[0] & 0xFFFF0000u),  0.f));
  p[2] = (short)f2bf(fmaxf(hacc[2]*inv + __uint_as_float(sv[1] << 16),          0.f));
  p[3] = (short)f2bf(fmaxf(hacc[3]*inv + __uint_as_float(sv[1] & 0xFFFF0000u),  0.f));
  p[4] = (short)f2bf(fmaxf(hacc[4]*inv + __uint_as_float(sv[2] << 16),          0.f));
  p[5] = (short)f2bf(fmaxf(hacc[5]*inv + __uint_as_float(sv[2] & 0xFFFF0000u),  0.f));
  p[6] = (short)f2bf(fmaxf(hacc[6]*inv + __uint_as_float(sv[3] << 16),          0.f));
  p[7] = (short)f2bf(fmaxf(hacc[7]*inv + __uint_as_float(sv[3] & 0xFFFF0000u),  0.f));
  *(bf16x8*)(S + (size_t)node*FDIM + g16*8) = p;   // h (cached: read by k_gemm2)
}

// ---------------- layer-2 dual GEMM on bf16 h (streaming) ----------------
// R15: H loads cached (L2-hot from k_agg1). Z2 stores cached; S2 stores NT.
__global__ __launch_bounds__(256, 2)
void k_gemm2(const unsigned short* __restrict__ H, const unsigned short* __restrict__ Wcat,
             const float* __restrict__ bl, const float* __restrict__ br,
             unsigned short* __restrict__ Z2, unsigned short* __restrict__ S,
             int N, int nrb){
  __shared__ unsigned short lds[64*FDIM];
  const int tid  = threadIdx.x;
  const int wave = tid >> 6;
  const int lane = tid & 63;
  const int n = lane & 15, q = lane >> 4;

  float bias[4];
#pragma unroll
  for (int ctl = 0; ctl < 4; ctl++){
    int ct = wave*4 + ctl;
    if (ct >= 8){ int col = (ct - 8)*16 + n; bias[ctl] = bl[col] + br[col]; }
    else bias[ctl] = 0.0f;
  }

  u32x4 pf[4];
  const int r_   = tid >> 4;
  const int c16_ = tid & 15;

  auto issue_load = [&](int rb){
    int row0 = rb*64;
#pragma unroll
    for (int it = 0; it < 4; it++){
      int gr = row0 + r_ + it*16;
      if (gr < N)
        pf[it] = *(const u32x4*)(H + (size_t)gr*FDIM + c16_*8);
      else
        pf[it] = (u32x4){0u,0u,0u,0u};
    }
  };

  int rb = blockIdx.x;
  if (rb < nrb) issue_load(rb);

  for (; rb < nrb; rb += gridDim.x){
    int row0 = rb*64;
    __syncthreads();
#pragma unroll
    for (int it = 0; it < 4; it++){
      int r = r_ + it*16;
      *(u32x4*)(lds + r*FDIM + ((c16_ ^ (r & 15)) * 8)) = pf[it];
    }
    __syncthreads();

    int rbn = rb + gridDim.x;
    if (rbn < nrb) issue_load(rbn);

    f32x4 acc[4][4];
#pragma unroll
    for (int rt = 0; rt < 4; rt++)
#pragma unroll
      for (int ctl = 0; ctl < 4; ctl++)
        acc[rt][ctl] = (f32x4){0.f, 0.f, 0.f, 0.f};

#pragma unroll
    for (int kk = 0; kk < 4; kk++){
      bf16x8 bfr[4];
#pragma unroll
      for (int ctl = 0; ctl < 4; ctl++){
        int row = (wave*4 + ctl)*16 + n;
        bfr[ctl] = *(const bf16x8*)(Wcat + row*FDIM + kk*32 + q*8);
      }
      bf16x8 afr[4];
#pragma unroll
      for (int rt = 0; rt < 4; rt++){
        int r = rt*16 + n;
        int c16 = (kk*4 + q) ^ n;
        afr[rt] = *(const bf16x8*)(lds + r*FDIM + c16*8);
      }
#pragma unroll
      for (int rt = 0; rt < 4; rt++)
#pragma unroll
        for (int ctl = 0; ctl < 4; ctl++)
          acc[rt][ctl] = __builtin_amdgcn_mfma_f32_16x16x32_bf16(
              afr[rt], bfr[ctl], acc[rt][ctl], 0, 0, 0);
    }

    unsigned short* dstb = (wave < 2) ? Z2 : S;
    int s0c = 64*(wave & 1) + n*4;
#pragma unroll
    for (int rt = 0; rt < 4; rt++){
#pragma unroll
      for (int r = 0; r < 4; r++){
        int grow = row0 + rt*16 + q*4 + r;
        if (grow < N){
          float v0 = acc[rt][0][r] + bias[0];
          float v1 = acc[rt][1][r] + bias[1];
          float v2 = acc[rt][2][r] + bias[2];
          float v3 = acc[rt][3][r] + bias[3];
          u32x2 u;
          u[0] = ((unsigned)f2bf(v1) << 16) | (unsigned)f2bf(v0);
          u[1] = ((unsigned)f2bf(v3) << 16) | (unsigned)f2bf(v2);
          u32x2* dp = (u32x2*)(dstb + (size_t)grow*FDIM + s0c);
          if (wave < 2) *dp = u;                         // Z2: cached
          else __builtin_nontemporal_store(u, dp);       // S2: stream
        }
      }
    }
  }
}

// ---------------- final aggregate: out = relu(sum(Z2[src])/deg + S2) ----------------
// Zero-LDS group-per-node shape; paired float2 un-permute stores (R15 win).
__global__ __launch_bounds__(256)
void k_aggregate(const unsigned short* __restrict__ Z2, const unsigned short* __restrict__ S,
                 const int* __restrict__ row_off, const int* __restrict__ cnt,
                 const int* __restrict__ csr_src, float* __restrict__ Out, int N){
  const int tid   = threadIdx.x;
  const int node  = blockIdx.x*16 + (tid >> 4);
  const int g16   = tid & 15;
  const int gbase = (tid & 63) & 48;
  if (node >= N) return;
  int ro   = row_off[node];
  int deg  = cnt[node];
  int pdeg = (deg + 7) & ~7;
  float inv = 1.0f / (float)(deg > 1 ? deg : 1);
  float hacc[8];
#pragma unroll
  for (int z = 0; z < 8; z++) hacc[z] = 0.f;

  for (int base = 0; base < pdeg; base += 16){
    int rem = pdeg - base;
    int sidx = (g16 < rem) ? csr_src[ro + base + g16] : N;
    {
      uint4 v[8];
#pragma unroll
      for (int t = 0; t < 8; t++){
        int id = __shfl(sidx, gbase + t);
        v[t] = *(const uint4*)(Z2 + (size_t)(unsigned)id*FDIM + g16*8);
      }
#pragma unroll
      for (int t = 0; t < 8; t++){
        hacc[0] += __uint_as_float(v[t].x << 16);
        hacc[1] += __uint_as_float(v[t].x & 0xFFFF0000u);
        hacc[2] += __uint_as_float(v[t].y << 16);
        hacc[3] += __uint_as_float(v[t].y & 0xFFFF0000u);
        hacc[4] += __uint_as_float(v[t].z << 16);
        hacc[5] += __uint_as_float(v[t].z & 0xFFFF0000u);
        hacc[6] += __uint_as_float(v[t].w << 16);
        hacc[7] += __uint_as_float(v[t].w & 0xFFFF0000u);
      }
    }
    if (rem > 8){
      uint4 v[8];
#pragma unroll
      for (int t = 0; t < 8; t++){
        int id = __shfl(sidx, gbase + 8 + t);
        v[t] = *(const uint4*)(Z2 + (size_t)(unsigned)id*FDIM + g16*8);
      }
#pragma unroll
      for (int t = 0; t < 8; t++){
        hacc[0] += __uint_as_float(v[t].x << 16);
        hacc[1] += __uint_as_float(v[t].x & 0xFFFF0000u);
        hacc[2] += __uint_as_float(v[t].y << 16);
        hacc[3] += __uint_as_float(v[t].y & 0xFFFF0000u);
        hacc[4] += __uint_as_float(v[t].z << 16);
        hacc[5] += __uint_as_float(v[t].z & 0xFFFF0000u);
        hacc[6] += __uint_as_float(v[t].w << 16);
        hacc[7] += __uint_as_float(v[t].w & 0xFFFF0000u);
      }
    }
  }

  u32x4 sv = __builtin_nontemporal_load((const u32x4*)(S + (size_t)node*FDIM + g16*8));
  float o[8];
  o[0] = fmaxf(hacc[0]*inv + __uint_as_float(sv[0] << 16),          0.f);
  o[1] = fmaxf(hacc[1]*inv + __uint_as_float(sv[0] & 0xFFFF0000u),  0.f);
  o[2] = fmaxf(hacc[2]*inv + __uint_as_float(sv[1] << 16),          0.f);
  o[3] = fmaxf(hacc[3]*inv + __uint_as_float(sv[1] & 0xFFFF0000u),  0.f);
  o[4] = fmaxf(hacc[4]*inv + __uint_as_float(sv[2] << 16),          0.f);
  o[5] = fmaxf(hacc[5]*inv + __uint_as_float(sv[2] & 0xFFFF0000u),  0.f);
  o[6] = fmaxf(hacc[6]*inv + __uint_as_float(sv[3] << 16),          0.f);
  o[7] = fmaxf(hacc[7]*inv + __uint_as_float(sv[3] & 0xFFFF0000u),  0.f);
  // un-permute via paired float2 stores: pair k = (o[k], o[k+4]) at base + k*16
  int obase = 64*(g16 >> 3) + (g16 & 7)*2;
#pragma unroll
  for (int k = 0; k < 4; k++){
    f32x2 w; w[0] = o[k]; w[1] = o[k+4];
    __builtin_nontemporal_store(w, (f32x2*)(Out + (size_t)node*FDIM + obase + k*16));
  }
}

extern "C" void kernel_launch(void* const* d_in, const int* in_sizes, int n_in,
                              void* d_out, int out_size, void* d_ws, size_t ws_size,
                              hipStream_t stream){
  const float* x   = (const float*)d_in[0];
  const int*   eix = (const int*)d_in[1];
  const float* Wl0 = (const float*)d_in[2];
  const float* bl0 = (const float*)d_in[3];
  const float* Wr0 = (const float*)d_in[4];
  const float* br0 = (const float*)d_in[5];
  const float* Wl1 = (const float*)d_in[6];
  const float* bl1 = (const float*)d_in[7];
  const float* Wr1 = (const float*)d_in[8];
  const float* br1 = (const float*)d_in[9];
  float* out = (float*)d_out;

  int N = in_sizes[0] / FDIM;
  int E = in_sizes[1] / 2;
  const int* src = eix;
  const int* dst = eix + E;

  // workspace (Z and Z2 have N+1 rows: row N is the zero dummy row)
  unsigned short* Z    = (unsigned short*)d_ws;
  unsigned short* Z2   = Z  + (size_t)(N + 1)*FDIM;
  unsigned short* S    = Z2 + (size_t)(N + 1)*FDIM;
  unsigned short* Wcat = S  + (size_t)N*FDIM;
  int* cnt     = (int*)(Wcat + 2*256*128);
  int* row_off = cnt + N;
  int* cursor  = row_off + N;
  int* csr_src = cursor + N;                 // capacity: E + 7N (padding bound)
  int* partials= csr_src + (E + 7*N);

  int nb = (N + 255)/256;

  k_init         <<<nb + 256, 256, 0, stream>>>(Wl0, Wr0, Wl1, Wr1, Wcat, cnt,
                                                Z + (size_t)N*FDIM, Z2 + (size_t)N*FDIM, N, nb);
  k_degree       <<<(E + 255)/256, 256, 0, stream>>>(dst, cnt, E);
  k_scan_blocks  <<<nb, 256, 0, stream>>>(cnt, row_off, partials, N);
  k_finalize_pad <<<nb, 256, 0, stream>>>(row_off, partials, cursor, cnt, csr_src, N);
  k_fill         <<<(E + 255)/256, 256, 0, stream>>>(src, dst, cursor, csr_src, E);

  int nrb  = (N + 63)/64;
  int ngrp = (N + 15)/16;
  k_dualgemm1<<<512, 256, 0, stream>>>(x, Wcat, bl0, br0, Z, S, N, nrb);
  k_agg1     <<<ngrp, 256, 0, stream>>>(Z, S, row_off, cnt, csr_src, N);
  k_gemm2    <<<512, 256, 0, stream>>>(S, Wcat + 256*128, bl1, br1, Z2, S, N, nrb);
  k_aggregate<<<ngrp, 256, 0, stream>>>(Z2, S, row_off, cnt, csr_src, out, N);
}